// Round 1
// baseline (338.413 us; speedup 1.0000x reference)
//
#include <hip/hip_runtime.h>

#define T_DIM 4096
#define C_DIM 512
#define E_DIM 1024
#define KW 15
#define LN_EPS 1e-5f

// ---------------------------------------------------------------------------
// Kernel 1: LayerNorm of the gate half (channels 512..1023 of each row).
// One 64-lane wave per (b,t) row. Each lane holds 8 values in registers
// (two float4 loads), wave shuffle-reduce for mean and variance.
// Writes normalized gate to ws laid out [B, T, C] (C=512) fp32.
// ---------------------------------------------------------------------------
__global__ __launch_bounds__(256) void fgu_ln_kernel(
    const float* __restrict__ x,
    const float* __restrict__ gamma,
    const float* __restrict__ beta,
    float* __restrict__ ln_out,
    int nrows)
{
    const int wave = (blockIdx.x * blockDim.x + threadIdx.x) >> 6;
    const int lane = threadIdx.x & 63;
    if (wave >= nrows) return;

    const float* g = x + (size_t)wave * E_DIM + C_DIM;  // gate half
    const int c0 = lane * 4;        // covers 0..255 across the wave
    const int c1 = 256 + lane * 4;  // covers 256..511

    const float4 a = *(const float4*)(g + c0);
    const float4 b = *(const float4*)(g + c1);

    // mean
    float s = a.x + a.y + a.z + a.w + b.x + b.y + b.z + b.w;
    #pragma unroll
    for (int off = 32; off; off >>= 1) s += __shfl_xor(s, off);
    const float mu = s * (1.0f / (float)C_DIM);

    // variance
    float dx, ss = 0.0f;
    dx = a.x - mu; ss += dx * dx;
    dx = a.y - mu; ss += dx * dx;
    dx = a.z - mu; ss += dx * dx;
    dx = a.w - mu; ss += dx * dx;
    dx = b.x - mu; ss += dx * dx;
    dx = b.y - mu; ss += dx * dx;
    dx = b.z - mu; ss += dx * dx;
    dx = b.w - mu; ss += dx * dx;
    #pragma unroll
    for (int off = 32; off; off >>= 1) ss += __shfl_xor(ss, off);
    const float rs = rsqrtf(ss * (1.0f / (float)C_DIM) + LN_EPS);

    const float4 ga = *(const float4*)(gamma + c0);
    const float4 gb = *(const float4*)(gamma + c1);
    const float4 ba = *(const float4*)(beta + c0);
    const float4 bb = *(const float4*)(beta + c1);

    float4 oa, ob;
    oa.x = (a.x - mu) * rs * ga.x + ba.x;
    oa.y = (a.y - mu) * rs * ga.y + ba.y;
    oa.z = (a.z - mu) * rs * ga.z + ba.z;
    oa.w = (a.w - mu) * rs * ga.w + ba.w;
    ob.x = (b.x - mu) * rs * gb.x + bb.x;
    ob.y = (b.y - mu) * rs * gb.y + bb.y;
    ob.z = (b.z - mu) * rs * gb.z + bb.z;
    ob.w = (b.w - mu) * rs * gb.w + bb.w;

    float* o = ln_out + (size_t)wave * C_DIM;
    *(float4*)(o + c0) = oa;
    *(float4*)(o + c1) = ob;
}

// ---------------------------------------------------------------------------
// Kernel 2: circular correlation along T (15 taps) + residual gating.
//   out[b,t,c] = res[b,t,c] * sum_{j=0..14} ln[b,(t+j)%T,c] * w[c,j]
// One 512-thread block per (b,t) row; thread = channel c. All ln reads are
// fully coalesced per row; the 15x re-read across t is served by L2/L3
// (ws is 67 MB < 256 MB Infinity Cache).
// ---------------------------------------------------------------------------
__global__ __launch_bounds__(512) void fgu_corr_kernel(
    const float* __restrict__ x,
    const float* __restrict__ ln,
    const float* __restrict__ w,
    float* __restrict__ out)
{
    const int row = blockIdx.x;        // b*T + t
    const int c   = threadIdx.x;       // 0..511
    const int b   = row >> 12;         // row / 4096
    const int t   = row & (T_DIM - 1);

    const float res = x[(size_t)row * E_DIM + c];

    // per-channel 15-tap weights (consecutive floats; L1-cached)
    float wreg[KW];
    const float* wc = w + c * KW;
    #pragma unroll
    for (int j = 0; j < KW; ++j) wreg[j] = wc[j];

    const float* lb = ln + (size_t)b * T_DIM * C_DIM;
    float acc = 0.0f;
    #pragma unroll
    for (int j = 0; j < KW; ++j) {
        int tt = t + j;
        if (tt >= T_DIM) tt -= T_DIM;
        acc += lb[(size_t)tt * C_DIM + c] * wreg[j];
    }

    out[(size_t)row * C_DIM + c] = res * acc;
}

extern "C" void kernel_launch(void* const* d_in, const int* in_sizes, int n_in,
                              void* d_out, int out_size, void* d_ws, size_t ws_size,
                              hipStream_t stream) {
    const float* x      = (const float*)d_in[0];   // [8, 4096, 1024]
    const float* weight = (const float*)d_in[1];   // [512, 15]
    const float* gamma  = (const float*)d_in[2];   // [512]
    const float* beta   = (const float*)d_in[3];   // [512]
    float* out = (float*)d_out;                    // [8, 4096, 512]
    float* ln_ws = (float*)d_ws;                   // [8, 4096, 512] fp32 = 64 MiB

    const int nrows = 8 * T_DIM;  // 32768

    // K1: 4 waves per 256-thread block -> nrows/4 blocks
    fgu_ln_kernel<<<nrows / 4, 256, 0, stream>>>(x, gamma, beta, ln_ws, nrows);

    // K2: one 512-thread block per row
    fgu_corr_kernel<<<nrows, 512, 0, stream>>>(x, ln_ws, weight, out);
}

// Round 2
// 274.928 us; speedup vs baseline: 1.2309x; 1.2309x over previous
//
#include <hip/hip_runtime.h>

#define T_DIM 4096
#define C_DIM 512
#define E_DIM 1024
#define KW 15
#define LN_EPS 1e-5f

#define TB 32                 // output rows per block (divides T_DIM)
#define RT (TB + KW - 1)      // rows loaded per block = 46
#define NW 8                  // waves per 512-thread block

// ---------------------------------------------------------------------------
// Fully fused: LayerNorm(gate) + 15-tap circular correlation along T + gating.
//   out[b,t,c] = res[b,t,c] * sum_j LN(gate)[b,(t+j)%T,c] * w[c,j]
// One 512-thread block per (b, 32-row tile); thread = channel c.
// Gate rows t0..t0+45 live in registers; LN stats computed in-block
// (wave shuffle partials over 64 channels -> 8-way LDS combine).
// ---------------------------------------------------------------------------
__global__ __launch_bounds__(512) void fgu_fused_kernel(
    const float* __restrict__ x,
    const float* __restrict__ w,
    const float* __restrict__ gamma,
    const float* __restrict__ beta,
    float* __restrict__ out)
{
    __shared__ float psum[RT][NW];
    __shared__ float pssq[RT][NW];
    __shared__ float smu[RT];
    __shared__ float srs[RT];

    const int c    = threadIdx.x;        // channel 0..511
    const int lane = c & 63;
    const int wv   = c >> 6;
    const int tile = blockIdx.x;         // b * (T/TB) + tidx
    const int b    = tile / (T_DIM / TB);
    const int t0   = (tile - b * (T_DIM / TB)) * TB;

    const float* xb = x + (size_t)b * T_DIM * E_DIM;

    // Load raw gate rows t0..t0+RT-1 (circular) and reduce per-row stats.
    float g[RT];
    #pragma unroll
    for (int k = 0; k < RT; ++k) {
        const int tt = (t0 + k) & (T_DIM - 1);
        g[k] = xb[(size_t)tt * E_DIM + C_DIM + c];
        float s  = g[k];
        float ss = g[k] * g[k];
        #pragma unroll
        for (int off = 32; off; off >>= 1) {
            s  += __shfl_xor(s, off);
            ss += __shfl_xor(ss, off);
        }
        if (lane == 0) { psum[k][wv] = s; pssq[k][wv] = ss; }
    }
    __syncthreads();

    if (c < RT) {
        float s = 0.0f, ss = 0.0f;
        #pragma unroll
        for (int i = 0; i < NW; ++i) { s += psum[c][i]; ss += pssq[c][i]; }
        const float mu  = s * (1.0f / (float)C_DIM);
        const float var = ss * (1.0f / (float)C_DIM) - mu * mu;
        smu[c] = mu;
        srs[c] = rsqrtf(var + LN_EPS);
    }
    __syncthreads();

    // Normalize in-register.
    const float gm = gamma[c];
    const float bt = beta[c];
    #pragma unroll
    for (int k = 0; k < RT; ++k)
        g[k] = (g[k] - smu[k]) * srs[k] * gm + bt;

    // Per-channel taps.
    float wreg[KW];
    const float* wc = w + c * KW;
    #pragma unroll
    for (int j = 0; j < KW; ++j) wreg[j] = wc[j];

    // Correlate + gate + store.
    const float* rb = xb + (size_t)t0 * E_DIM + c;                     // residual
    float*       ob = out + ((size_t)b * T_DIM + t0) * C_DIM + c;
    #pragma unroll
    for (int i = 0; i < TB; ++i) {
        float acc = 0.0f;
        #pragma unroll
        for (int j = 0; j < KW; ++j)
            acc = fmaf(g[i + j], wreg[j], acc);
        ob[(size_t)i * C_DIM] = rb[(size_t)i * E_DIM] * acc;
    }
}

extern "C" void kernel_launch(void* const* d_in, const int* in_sizes, int n_in,
                              void* d_out, int out_size, void* d_ws, size_t ws_size,
                              hipStream_t stream) {
    const float* x      = (const float*)d_in[0];   // [8, 4096, 1024]
    const float* weight = (const float*)d_in[1];   // [512, 15]
    const float* gamma  = (const float*)d_in[2];   // [512]
    const float* beta   = (const float*)d_in[3];   // [512]
    float* out = (float*)d_out;                    // [8, 4096, 512]

    const int nblocks = 8 * (T_DIM / TB);          // 1024
    fgu_fused_kernel<<<nblocks, 512, 0, stream>>>(x, weight, gamma, beta, out);
}

// Round 3
// 230.292 us; speedup vs baseline: 1.4695x; 1.1938x over previous
//
#include <hip/hip_runtime.h>

#define T_DIM 4096
#define C_DIM 512
#define E_DIM 1024
#define KW 15
#define LN_EPS 1e-5f

#define TB 16                 // output rows per block (divides T_DIM)
#define RT (TB + KW - 1)      // staged rows per block = 30
#define NW 8                  // waves per 512-thread block

// ---------------------------------------------------------------------------
// Prep: fold gamma/beta into the taps.
//   wpad[c][j]  = gamma[c] * w[c][j]          (j = 0..14)
//   wpad[c][15] = beta[c]  * sum_j w[c][j]
// ---------------------------------------------------------------------------
__global__ __launch_bounds__(512) void fgu_prep_kernel(
    const float* __restrict__ w,
    const float* __restrict__ gamma,
    const float* __restrict__ beta,
    float* __restrict__ wpad)
{
    const int c = threadIdx.x;           // one block of 512
    const float gm = gamma[c];
    const float bt = beta[c];
    float s = 0.0f;
    float* o = wpad + c * 16;
    #pragma unroll
    for (int j = 0; j < KW; ++j) {
        const float wj = w[c * KW + j];
        s += wj;
        o[j] = gm * wj;
    }
    o[KW] = bt * s;
}

// ---------------------------------------------------------------------------
// Fused LN + 15-tap circular correlation + residual gate.
// Phase 1: each wave stats+stages whole rows (8 elems/lane, 12 shuffles/row).
// Phase 2: thread = channel; normalize 30 staged rows once into z[30] regs,
//          then 16 outputs x 15-fma dot, gate with residual, store.
// ---------------------------------------------------------------------------
__global__ __launch_bounds__(512) void fgu_fused_kernel(
    const float* __restrict__ x,
    const float* __restrict__ wpad,
    float* __restrict__ out)
{
    __shared__ float  tile[RT][C_DIM];   // raw gate rows
    __shared__ float2 srn[RT];           // (rsigma, -mu*rsigma) per row

    const int tid  = threadIdx.x;
    const int lane = tid & 63;
    const int wv   = tid >> 6;
    const int b    = blockIdx.x >> 8;            // T_DIM/TB = 256 tiles per b
    const int t0   = (blockIdx.x & 255) * TB;

    const float* xb = x + (size_t)b * T_DIM * E_DIM;

    // ---- Phase 1: stage raw gate rows + per-row LN stats (one wave per row)
    for (int k = wv; k < RT; k += NW) {
        const int tt = (t0 + k) & (T_DIM - 1);
        const float* gp = xb + (size_t)tt * E_DIM + C_DIM;
        const float4 a  = *(const float4*)(gp + lane * 4);
        const float4 b4 = *(const float4*)(gp + 256 + lane * 4);

        float s  = a.x + a.y + a.z + a.w + b4.x + b4.y + b4.z + b4.w;
        float ss = a.x*a.x + a.y*a.y + a.z*a.z + a.w*a.w
                 + b4.x*b4.x + b4.y*b4.y + b4.z*b4.z + b4.w*b4.w;
        #pragma unroll
        for (int off = 32; off; off >>= 1) {
            s  += __shfl_xor(s, off);
            ss += __shfl_xor(ss, off);
        }

        *(float4*)&tile[k][lane * 4]       = a;
        *(float4*)&tile[k][256 + lane * 4] = b4;

        if (lane == 0) {
            const float mu  = s * (1.0f / (float)C_DIM);
            const float var = ss * (1.0f / (float)C_DIM) - mu * mu;
            const float rs  = rsqrtf(var + LN_EPS);
            srn[k] = make_float2(rs, -mu * rs);
        }
    }
    __syncthreads();

    // ---- Phase 2: per-channel correlation
    const int c = tid;

    float z[RT];
    #pragma unroll
    for (int k = 0; k < RT; ++k) {
        const float2 p = srn[k];
        z[k] = fmaf(tile[k][c], p.x, p.y);   // (g - mu) * rsigma
    }

    // folded taps: wr[j] = gamma*w, wr[15] = beta*sum(w)
    float wr[16];
    {
        const float4* wp = (const float4*)(wpad + c * 16);
        const float4 w0 = wp[0], w1 = wp[1], w2 = wp[2], w3 = wp[3];
        wr[0]=w0.x;  wr[1]=w0.y;  wr[2]=w0.z;  wr[3]=w0.w;
        wr[4]=w1.x;  wr[5]=w1.y;  wr[6]=w1.z;  wr[7]=w1.w;
        wr[8]=w2.x;  wr[9]=w2.y;  wr[10]=w2.z; wr[11]=w2.w;
        wr[12]=w3.x; wr[13]=w3.y; wr[14]=w3.z; wr[15]=w3.w;
    }

    const float* rb = xb + (size_t)t0 * E_DIM + c;                 // residual
    float*       ob = out + ((size_t)b * T_DIM + t0) * C_DIM + c;
    #pragma unroll
    for (int i = 0; i < TB; ++i) {
        float acc = wr[KW];                 // beta * sum(w) bias term
        #pragma unroll
        for (int j = 0; j < KW; ++j)
            acc = fmaf(z[i + j], wr[j], acc);
        ob[(size_t)i * C_DIM] = rb[(size_t)i * E_DIM] * acc;
    }
}

extern "C" void kernel_launch(void* const* d_in, const int* in_sizes, int n_in,
                              void* d_out, int out_size, void* d_ws, size_t ws_size,
                              hipStream_t stream) {
    const float* x      = (const float*)d_in[0];   // [8, 4096, 1024]
    const float* weight = (const float*)d_in[1];   // [512, 15]
    const float* gamma  = (const float*)d_in[2];   // [512]
    const float* beta   = (const float*)d_in[3];   // [512]
    float* out  = (float*)d_out;                   // [8, 4096, 512]
    float* wpad = (float*)d_ws;                    // [512][16] = 32 KB

    fgu_prep_kernel<<<1, 512, 0, stream>>>(weight, gamma, beta, wpad);

    const int nblocks = 8 * (T_DIM / TB);          // 2048
    fgu_fused_kernel<<<nblocks, 512, 0, stream>>>(x, wpad, out);
}